// Round 4
// baseline (298.055 us; speedup 1.0000x reference)
//
#include <hip/hip_runtime.h>
#include <hip/hip_bf16.h>

#define WSZ 7
#define WD  49
#define NH  8
#define NWIN 64
#define HH  56
#define SS  3
#define TOK 3136
#define EMB 256

typedef __attribute__((ext_vector_type(8))) short bf16x8;
typedef __attribute__((ext_vector_type(8))) unsigned short u16x8;
typedef __attribute__((ext_vector_type(4))) float f32x4;

// ---- LDS layout (dynamic shared, 73376 B -> 2 blocks/CU) ----
#define OFF_WT   0                     // qkv w^T: 96 x 40 bf16 = 7680
#define OFF_BIAS 7680                  // 96 f32
#define OFF_RPB  8064                  // 169*8 f32 = 5408
#define OFF_REG  13472                 // 64 int
#define OFF_POS  13728                 // 64 int
#define OFF_PW   13984                 // per-wave scratch x4 (phase1) / sO tile (phase2, aliased)
#define PW_SZ    14848                 // Q(5120)+K(5120) [P(9216) aliases] + VT(4608)
#define PW_K     5120
#define PW_VT    10240
#define LDS_TOTAL (OFF_PW + 4*PW_SZ)   // 73376
// phase-2 O tile: 64 tok x 264 bf16 (=33792 B) aliases the per-wave scratch
#define SO_STRIDE 264

__device__ __forceinline__ unsigned short f2bf(float f) {
    union { float f; unsigned u; } v; v.f = f;
    return (unsigned short)((v.u + 0x7FFFu + ((v.u >> 16) & 1u)) >> 16);
}
__device__ __forceinline__ unsigned long long pack4(float a, float b, float c, float d) {
    return (unsigned long long)f2bf(a) | ((unsigned long long)f2bf(b) << 16)
         | ((unsigned long long)f2bf(c) << 32) | ((unsigned long long)f2bf(d) << 48);
}

// One block per (b, window): 4 waves. Phase 1: wave w computes attention for
// heads 2w,2w+1. Phase 2: wave w computes output columns [64w, 64w+64).
__global__ __launch_bounds__(256, 2) void fused_kernel(
    const float* __restrict__ x, const float* __restrict__ qkv_w,
    const float* __restrict__ qkv_b, const float* __restrict__ rpb,
    const unsigned short* __restrict__ Wt,   // proj_w^T bf16: Wt[n][k]
    const float* __restrict__ proj_b,
    float* __restrict__ out)
{
    extern __shared__ char smem[];
    unsigned short* sWT = (unsigned short*)(smem + OFF_WT);
    float* sBias = (float*)(smem + OFF_BIAS);
    float* sRPB  = (float*)(smem + OFF_RPB);
    int*   sREG  = (int*)(smem + OFF_REG);
    int*   sPOS  = (int*)(smem + OFF_POS);

    const int tid = threadIdx.x;
    const int w = blockIdx.x & 63, b = blockIdx.x >> 6;
    const int wi = w >> 3, wj = w & 7;

    if (tid < 64) {
        int ti = tid / 7, tj = tid - (tid / 7) * 7;
        int sh = wi * WSZ + ti, sw = wj * WSZ + tj;
        int rr = (sh < HH - WSZ) ? 0 : (sh < HH - SS) ? 1 : 2;
        int rc = (sw < HH - WSZ) ? 0 : (sw < HH - SS) ? 1 : 2;
        sREG[tid] = rr * 3 + rc;
        sPOS[tid] = ((sh + SS) % HH) * HH + ((sw + SS) % HH);
    }
    for (int i = tid; i < 32 * 96; i += 256) {
        int c = i / 96, j = i - c * 96;
        sWT[j * 40 + c] = f2bf(qkv_w[i]);
    }
    for (int i = tid; i < 96; i += 256) sBias[i] = qkv_b[i];
    for (int i = tid; i < 169 * NH; i += 256) sRPB[i] = rpb[i];
    __syncthreads();

    const int wave = tid >> 6, lane = tid & 63;
    const int cl = lane & 15, quad = lane >> 4;
    unsigned short* sQ  = (unsigned short*)(smem + OFF_PW + wave * PW_SZ);
    unsigned short* sK  = sQ + PW_K / 2;
    unsigned short* sVT = sQ + PW_VT / 2;
    unsigned short* sP  = sQ;   // aliases Q+K (dead by then)

    const float* xrow[4];
    #pragma unroll
    for (int mt = 0; mt < 4; ++mt) {
        int tok = mt * 16 + cl;
        xrow[mt] = x + ((size_t)b * TOK + sPOS[tok]) * EMB + quad * 8;
    }
    int ki[4], kj[4], kreg[4];
    #pragma unroll
    for (int nt = 0; nt < 4; ++nt) {
        int kt = nt * 16 + cl;
        ki[nt] = kt / 7; kj[nt] = kt - ki[nt] * 7;
        kreg[nt] = sREG[kt];
    }
    const float qscale = 0.17677669529663687f;  // 1/sqrt(32)

    f32x4 otr[2][2][4];   // [head][mv][nt] O^T fragments, kept until phase 2

    #pragma unroll
    for (int hi = 0; hi < 2; ++hi) {
        const int h = wave * 2 + hi;
        // ---------- qkv: (64x32) @ (32x96), A-frags straight from global ----------
        bf16x8 xa[4];
        #pragma unroll
        for (int mt = 0; mt < 4; ++mt) {
            const float* p = xrow[mt] + h * 32;
            float4 v0 = *(const float4*)p, v1 = *(const float4*)(p + 4);
            union { bf16x8 v; unsigned long long q[2]; } u;
            u.q[0] = pack4(v0.x, v0.y, v0.z, v0.w);
            u.q[1] = pack4(v1.x, v1.y, v1.z, v1.w);
            xa[mt] = u.v;
        }
        #pragma unroll
        for (int nt = 0; nt < 6; ++nt) {
            bf16x8 wb = *(const bf16x8*)(&sWT[(nt * 16 + cl) * 40 + quad * 8]);
            float bias = sBias[nt * 16 + cl];
            #pragma unroll
            for (int mt = 0; mt < 4; ++mt) {
                f32x4 c = {bias, bias, bias, bias};
                c = __builtin_amdgcn_mfma_f32_16x16x32_bf16(xa[mt], wb, c, 0, 0, 0);
                int tok0 = mt * 16 + quad * 4;
                if (nt < 2) {
                    int col = nt * 16 + cl;
                    #pragma unroll
                    for (int r = 0; r < 4; ++r)
                        sQ[(tok0 + r) * 40 + col] = f2bf(c[r] * qscale);
                } else if (nt < 4) {
                    int col = nt * 16 + cl - 32;
                    #pragma unroll
                    for (int r = 0; r < 4; ++r)
                        sK[(tok0 + r) * 40 + col] = f2bf(c[r]);
                } else {
                    int hd = nt * 16 + cl - 64;   // V^T[hd][tok]
                    *(unsigned long long*)(&sVT[hd * 72 + tok0]) =
                        pack4(c[0], c[1], c[2], c[3]);
                }
            }
        }
        // ---------- scores: Q @ K^T (64x64, K=32) ----------
        bf16x8 qa[4], kb[4];
        #pragma unroll
        for (int mt = 0; mt < 4; ++mt) qa[mt] = *(const bf16x8*)(&sQ[(mt * 16 + cl) * 40 + quad * 8]);
        #pragma unroll
        for (int nt = 0; nt < 4; ++nt) kb[nt] = *(const bf16x8*)(&sK[(nt * 16 + cl) * 40 + quad * 8]);
        f32x4 sc[4][4];
        #pragma unroll
        for (int mt = 0; mt < 4; ++mt)
            #pragma unroll
            for (int nt = 0; nt < 4; ++nt) {
                f32x4 z = {0.f, 0.f, 0.f, 0.f};
                sc[mt][nt] = __builtin_amdgcn_mfma_f32_16x16x32_bf16(qa[mt], kb[nt], z, 0, 0, 0);
            }
        // ---------- softmax (scores bounded, no max pass) + write P ----------
        #pragma unroll
        for (int mt = 0; mt < 4; ++mt) {
            #pragma unroll
            for (int r = 0; r < 4; ++r) {
                int qt = mt * 16 + quad * 4 + r;
                int qi = qt / 7, qj = qt - qi * 7;
                int qreg = sREG[qt];
                float pv[4], sm = 0.f;
                #pragma unroll
                for (int nt = 0; nt < 4; ++nt) {
                    int kt = nt * 16 + cl;
                    float v = sc[mt][nt][r];
                    int idx = (qi - ki[nt] + 6) * 13 + (qj - kj[nt] + 6);
                    idx = idx < 0 ? 0 : (idx > 168 ? 168 : idx);
                    v += sRPB[idx * NH + h];
                    if (kreg[nt] != qreg) v -= 100.f;
                    if (kt >= WD) v = -1e30f;
                    v = __expf(v);
                    pv[nt] = v; sm += v;
                }
                sm += __shfl_xor(sm, 1, 16);
                sm += __shfl_xor(sm, 2, 16);
                sm += __shfl_xor(sm, 4, 16);
                sm += __shfl_xor(sm, 8, 16);
                float inv = 1.f / sm;
                #pragma unroll
                for (int nt = 0; nt < 4; ++nt)
                    sP[qt * 72 + nt * 16 + cl] = f2bf(pv[nt] * inv);
            }
        }
        // ---------- PV as O^T = V^T @ P^T, kept in registers ----------
        #pragma unroll
        for (int mv = 0; mv < 2; ++mv)
            #pragma unroll
            for (int nt = 0; nt < 4; ++nt) otr[hi][mv][nt] = (f32x4){0.f, 0.f, 0.f, 0.f};
        #pragma unroll
        for (int ks = 0; ks < 2; ++ks) {
            bf16x8 va[2], pb[4];
            #pragma unroll
            for (int mv = 0; mv < 2; ++mv)
                va[mv] = *(const bf16x8*)(&sVT[(mv * 16 + cl) * 72 + ks * 32 + quad * 8]);
            #pragma unroll
            for (int nt = 0; nt < 4; ++nt)
                pb[nt] = *(const bf16x8*)(&sP[(nt * 16 + cl) * 72 + ks * 32 + quad * 8]);
            #pragma unroll
            for (int mv = 0; mv < 2; ++mv)
                #pragma unroll
                for (int nt = 0; nt < 4; ++nt)
                    otr[hi][mv][nt] = __builtin_amdgcn_mfma_f32_16x16x32_bf16(va[mv], pb[nt], otr[hi][mv][nt], 0, 0, 0);
        }
    }

    // ---------- phase 2: projection. sO tile aliases dead per-wave scratch ----------
    __syncthreads();
    unsigned short* sO = (unsigned short*)(smem + OFF_PW);
    #pragma unroll
    for (int hi = 0; hi < 2; ++hi) {
        const int h = wave * 2 + hi;
        #pragma unroll
        for (int mv = 0; mv < 2; ++mv)
            #pragma unroll
            for (int nt = 0; nt < 4; ++nt) {
                int qt = nt * 16 + cl;
                f32x4 o = otr[hi][mv][nt];
                *(unsigned long long*)(&sO[qt * SO_STRIDE + h * 32 + mv * 16 + quad * 4]) =
                    pack4(o[0], o[1], o[2], o[3]);
            }
    }
    __syncthreads();

    // OUT^T = Wt * O : per wave, 64 output cols n in [64*wave, 64*wave+64)
    const int n0 = wave * 64;
    f32x4 acc[4][4];   // [n-mtile][tok-ntile]
    #pragma unroll
    for (int mt = 0; mt < 4; ++mt)
        #pragma unroll
        for (int tt = 0; tt < 4; ++tt) acc[mt][tt] = (f32x4){0.f, 0.f, 0.f, 0.f};
    #pragma unroll
    for (int ks = 0; ks < 8; ++ks) {
        bf16x8 wa[4], ob[4];
        #pragma unroll
        for (int mt = 0; mt < 4; ++mt)
            wa[mt] = *(const bf16x8*)(Wt + (size_t)(n0 + mt * 16 + cl) * 256 + ks * 32 + quad * 8);
        #pragma unroll
        for (int tt = 0; tt < 4; ++tt)
            ob[tt] = *(const bf16x8*)(&sO[(tt * 16 + cl) * SO_STRIDE + ks * 32 + quad * 8]);
        #pragma unroll
        for (int mt = 0; mt < 4; ++mt)
            #pragma unroll
            for (int tt = 0; tt < 4; ++tt)
                acc[mt][tt] = __builtin_amdgcn_mfma_f32_16x16x32_bf16(wa[mt], ob[tt], acc[mt][tt], 0, 0, 0);
    }
    // epilogue: acc[mt][tt][r] = OUT[tok = tt*16+cl][n = n0 + mt*16 + quad*4 + r]
    #pragma unroll
    for (int mt = 0; mt < 4; ++mt) {
        float4 bq = *(const float4*)(proj_b + n0 + mt * 16 + quad * 4);
        #pragma unroll
        for (int tt = 0; tt < 4; ++tt) {
            int tok = tt * 16 + cl;
            if (tok < WD) {
                f32x4 v = acc[mt][tt];
                v[0] += bq.x; v[1] += bq.y; v[2] += bq.z; v[3] += bq.w;
                float* dst = out + ((size_t)b * TOK + sPOS[tok]) * EMB + n0 + mt * 16 + quad * 4;
                *(f32x4*)dst = v;
            }
        }
    }
}

// ---------------- proj_w fp32 -> bf16 transpose: Wt[n][k] = bf16(W[k][n]) ------
__global__ __launch_bounds__(256) void cvt_kernel(
    const float* __restrict__ W, unsigned short* __restrict__ Wt)
{
    int i = blockIdx.x * 256 + threadIdx.x;     // 65536 elems
    int k = i >> 8, n = i & 255;
    Wt[n * 256 + k] = f2bf(W[i]);
}

extern "C" void kernel_launch(void* const* d_in, const int* in_sizes, int n_in,
                              void* d_out, int out_size, void* d_ws, size_t ws_size,
                              hipStream_t stream) {
    const float* x      = (const float*)d_in[0];
    const float* qkv_w  = (const float*)d_in[1];
    const float* qkv_b  = (const float*)d_in[2];
    const float* proj_w = (const float*)d_in[3];
    const float* proj_b = (const float*)d_in[4];
    const float* rpb    = (const float*)d_in[5];
    float* out = (float*)d_out;

    const int B = in_sizes[0] / (TOK * EMB);

    unsigned short* Wt = (unsigned short*)d_ws;   // 256*256 bf16 = 128 KB

    (void)hipFuncSetAttribute(reinterpret_cast<const void*>(&fused_kernel),
                              hipFuncAttributeMaxDynamicSharedMemorySize, LDS_TOTAL);
    cvt_kernel<<<256, 256, 0, stream>>>(proj_w, Wt);
    fused_kernel<<<B * NWIN, 256, LDS_TOTAL, stream>>>(x, qkv_w, qkv_b, rpb, Wt, proj_b, out);
}

// Round 5
// 257.120 us; speedup vs baseline: 1.1592x; 1.1592x over previous
//
#include <hip/hip_runtime.h>
#include <hip/hip_bf16.h>

#define WSZ 7
#define WD  49
#define NH  8
#define NWIN 64
#define HH  56
#define SS  3
#define TOK 3136
#define EMB 256

typedef __attribute__((ext_vector_type(8))) short bf16x8;
typedef __attribute__((ext_vector_type(8))) unsigned short u16x8;
typedef __attribute__((ext_vector_type(4))) float f32x4;

// ---- LDS layout (dynamic shared, 67328 B -> 2 blocks/CU) ----
#define OFF_WT   0                     // qkv w^T: 96 x 40 bf16 = 7680
#define OFF_POS  7680                  // 64 int
#define OFF_PW   7936                  // per-wave scratch x4 (phase1) / sO tile (phase2)
#define PW_SZ    14848                 // Q(5120)+K(5120) [P(9216) aliases] + VT(4608)
#define PW_K     5120
#define PW_VT    10240
#define LDS_TOTAL (OFF_PW + 4*PW_SZ)   // 67328
#define SO_STRIDE 264                  // phase-2 O tile: 64 x 264 bf16 aliases scratch

__device__ __forceinline__ unsigned short f2bf(float f) {
    union { float f; unsigned u; } v; v.f = f;
    return (unsigned short)((v.u + 0x7FFFu + ((v.u >> 16) & 1u)) >> 16);
}
__device__ __forceinline__ unsigned long long pack4(float a, float b, float c, float d) {
    return (unsigned long long)f2bf(a) | ((unsigned long long)f2bf(b) << 16)
         | ((unsigned long long)f2bf(c) << 32) | ((unsigned long long)f2bf(d) << 48);
}

// One block per (b, window): 4 waves. Phase 1: wave w -> heads 2w,2w+1.
// Phase 2: wave w -> output columns [64w, 64w+64).
__global__ __launch_bounds__(256, 2) void fused_kernel(
    const float* __restrict__ x, const float* __restrict__ qkv_w,
    const float* __restrict__ qkv_b, const unsigned short* __restrict__ Wt,
    const float* __restrict__ proj_b, const float* __restrict__ tbl,
    float* __restrict__ out)
{
    extern __shared__ char smem[];
    unsigned short* sWT = (unsigned short*)(smem + OFF_WT);
    int* sPOS = (int*)(smem + OFF_POS);

    const int tid = threadIdx.x;
    const int w = blockIdx.x & 63, b = blockIdx.x >> 6;
    const int wi = w >> 3, wj = w & 7;
    const int cls = (((wi == 7) ? 1 : 0) << 1) | ((wj == 7) ? 1 : 0);

    if (tid < 64) {
        int ti = tid / 7, tj = tid - (tid / 7) * 7;
        int sh = wi * WSZ + ti, sw = wj * WSZ + tj;
        sPOS[tid] = ((sh + SS) % HH) * HH + ((sw + SS) % HH);
    }
    for (int i = tid; i < 32 * 96; i += 256) {
        int c = i / 96, j = i - c * 96;
        sWT[j * 40 + c] = f2bf(qkv_w[i]);
    }
    __syncthreads();

    const int wave = tid >> 6, lane = tid & 63;
    const int cl = lane & 15, quad = lane >> 4;
    unsigned short* sQ  = (unsigned short*)(smem + OFF_PW + wave * PW_SZ);
    unsigned short* sK  = sQ + PW_K / 2;
    unsigned short* sVT = sQ + PW_VT / 2;
    unsigned short* sP  = sQ;   // aliases Q+K (dead by then)

    const float* xrow[4];
    #pragma unroll
    for (int mt = 0; mt < 4; ++mt)
        xrow[mt] = x + ((size_t)b * TOK + sPOS[mt * 16 + cl]) * EMB + quad * 8;

    const float qscale = 0.17677669529663687f;  // 1/sqrt(32)
    f32x4 otr[2][2][4];   // [head][mv][nt] O^T fragments

    #pragma unroll
    for (int hi = 0; hi < 2; ++hi) {
        const int h = wave * 2 + hi;
        // ---- x fragments (token tiles), built from global ----
        bf16x8 xa[4];
        #pragma unroll
        for (int mt = 0; mt < 4; ++mt) {
            const float* p = xrow[mt] + h * 32;
            float4 v0 = *(const float4*)p, v1 = *(const float4*)(p + 4);
            union { bf16x8 v; unsigned long long q[2]; } u;
            u.q[0] = pack4(v0.x, v0.y, v0.z, v0.w);
            u.q[1] = pack4(v1.x, v1.y, v1.z, v1.w);
            xa[mt] = u.v;
        }
        // ---- Q,K transposed: D[m=outcol][n=token] -> packed b64 token-major stores ----
        #pragma unroll
        for (int mt = 0; mt < 4; ++mt) {          // outcol tiles 0..3 (Q: 0,1; K: 2,3)
            bf16x8 wa = *(const bf16x8*)(&sWT[(mt * 16 + cl) * 40 + quad * 8]);
            float4 bq = *(const float4*)(qkv_b + mt * 16 + quad * 4);
            #pragma unroll
            for (int nt = 0; nt < 4; ++nt) {      // token tiles
                f32x4 c = {bq.x, bq.y, bq.z, bq.w};
                c = __builtin_amdgcn_mfma_f32_16x16x32_bf16(wa, xa[nt], c, 0, 0, 0);
                int tok = nt * 16 + cl;
                if (mt < 2) {
                    int col0 = mt * 16 + quad * 4;
                    *(unsigned long long*)(&sQ[tok * 40 + col0]) =
                        pack4(c[0] * qscale, c[1] * qscale, c[2] * qscale, c[3] * qscale);
                } else {
                    int col0 = (mt - 2) * 16 + quad * 4;
                    *(unsigned long long*)(&sK[tok * 40 + col0]) =
                        pack4(c[0], c[1], c[2], c[3]);
                }
            }
        }
        // ---- V original orientation: D[m=token][n=outcol] -> V^T b64 stores ----
        #pragma unroll
        for (int nt = 4; nt < 6; ++nt) {
            bf16x8 wv = *(const bf16x8*)(&sWT[(nt * 16 + cl) * 40 + quad * 8]);
            float bb = qkv_b[nt * 16 + cl];
            #pragma unroll
            for (int mt = 0; mt < 4; ++mt) {
                f32x4 c = {bb, bb, bb, bb};
                c = __builtin_amdgcn_mfma_f32_16x16x32_bf16(xa[mt], wv, c, 0, 0, 0);
                int hd = nt * 16 + cl - 64;
                *(unsigned long long*)(&sVT[hd * 72 + mt * 16 + quad * 4]) =
                    pack4(c[0], c[1], c[2], c[3]);
            }
        }
        // ---- scores transposed: scT = K·Q^T + tbl; D[m=ktok][n=qtok] ----
        bf16x8 kb[4], qa[4];
        #pragma unroll
        for (int mt = 0; mt < 4; ++mt) kb[mt] = *(const bf16x8*)(&sK[(mt * 16 + cl) * 40 + quad * 8]);
        #pragma unroll
        for (int nt = 0; nt < 4; ++nt) qa[nt] = *(const bf16x8*)(&sQ[(nt * 16 + cl) * 40 + quad * 8]);
        const float* tb = tbl + ((size_t)(cls * 8 + h) * 16) * 256 + lane * 4;
        f32x4 sc[4][4];
        #pragma unroll
        for (int mt = 0; mt < 4; ++mt)
            #pragma unroll
            for (int nt = 0; nt < 4; ++nt) {
                f32x4 c = *(const f32x4*)(tb + (mt * 4 + nt) * 256);
                sc[mt][nt] = __builtin_amdgcn_mfma_f32_16x16x32_bf16(kb[mt], qa[nt], c, 0, 0, 0);
            }
        // ---- softmax: per lane, qtok = nt*16+cl; keys in-lane (16) + cross-quad ----
        #pragma unroll
        for (int nt = 0; nt < 4; ++nt) {
            float e[4][4];
            float sm = 0.f;
            #pragma unroll
            for (int mt = 0; mt < 4; ++mt)
                #pragma unroll
                for (int r = 0; r < 4; ++r) {
                    float v = __expf(sc[mt][nt][r]);
                    e[mt][r] = v; sm += v;
                }
            sm += __shfl_xor(sm, 16);
            sm += __shfl_xor(sm, 32);
            float inv = 1.f / sm;
            int qt = nt * 16 + cl;
            #pragma unroll
            for (int mt = 0; mt < 4; ++mt)
                *(unsigned long long*)(&sP[qt * 72 + mt * 16 + quad * 4]) =
                    pack4(e[mt][0] * inv, e[mt][1] * inv, e[mt][2] * inv, e[mt][3] * inv);
        }
        // ---- PV: O^T = V^T · P^T ----
        #pragma unroll
        for (int mv = 0; mv < 2; ++mv)
            #pragma unroll
            for (int nt = 0; nt < 4; ++nt) otr[hi][mv][nt] = (f32x4){0.f, 0.f, 0.f, 0.f};
        #pragma unroll
        for (int ks = 0; ks < 2; ++ks) {
            bf16x8 va[2], pb[4];
            #pragma unroll
            for (int mv = 0; mv < 2; ++mv)
                va[mv] = *(const bf16x8*)(&sVT[(mv * 16 + cl) * 72 + ks * 32 + quad * 8]);
            #pragma unroll
            for (int nt = 0; nt < 4; ++nt)
                pb[nt] = *(const bf16x8*)(&sP[(nt * 16 + cl) * 72 + ks * 32 + quad * 8]);
            #pragma unroll
            for (int mv = 0; mv < 2; ++mv)
                #pragma unroll
                for (int nt = 0; nt < 4; ++nt)
                    otr[hi][mv][nt] = __builtin_amdgcn_mfma_f32_16x16x32_bf16(va[mv], pb[nt], otr[hi][mv][nt], 0, 0, 0);
        }
    }

    // ---------- phase 2: projection ----------
    __syncthreads();
    unsigned short* sO = (unsigned short*)(smem + OFF_PW);
    #pragma unroll
    for (int hi = 0; hi < 2; ++hi) {
        const int h = wave * 2 + hi;
        #pragma unroll
        for (int mv = 0; mv < 2; ++mv)
            #pragma unroll
            for (int nt = 0; nt < 4; ++nt) {
                int qt = nt * 16 + cl;
                f32x4 o = otr[hi][mv][nt];
                *(unsigned long long*)(&sO[qt * SO_STRIDE + h * 32 + mv * 16 + quad * 4]) =
                    pack4(o[0], o[1], o[2], o[3]);
            }
    }
    __syncthreads();

    const int n0 = wave * 64;
    f32x4 acc[4][4];
    #pragma unroll
    for (int mt = 0; mt < 4; ++mt)
        #pragma unroll
        for (int tt = 0; tt < 4; ++tt) acc[mt][tt] = (f32x4){0.f, 0.f, 0.f, 0.f};
    #pragma unroll
    for (int ks = 0; ks < 8; ++ks) {
        bf16x8 wa[4], ob[4];
        #pragma unroll
        for (int mt = 0; mt < 4; ++mt)
            wa[mt] = *(const bf16x8*)(Wt + (size_t)(n0 + mt * 16 + cl) * 256 + ks * 32 + quad * 8);
        #pragma unroll
        for (int tt = 0; tt < 4; ++tt)
            ob[tt] = *(const bf16x8*)(&sO[(tt * 16 + cl) * SO_STRIDE + ks * 32 + quad * 8]);
        #pragma unroll
        for (int mt = 0; mt < 4; ++mt)
            #pragma unroll
            for (int tt = 0; tt < 4; ++tt)
                acc[mt][tt] = __builtin_amdgcn_mfma_f32_16x16x32_bf16(wa[mt], ob[tt], acc[mt][tt], 0, 0, 0);
    }
    #pragma unroll
    for (int mt = 0; mt < 4; ++mt) {
        float4 bq = *(const float4*)(proj_b + n0 + mt * 16 + quad * 4);
        #pragma unroll
        for (int tt = 0; tt < 4; ++tt) {
            int tok = tt * 16 + cl;
            if (tok < WD) {
                f32x4 v = acc[mt][tt];
                v[0] += bq.x; v[1] += bq.y; v[2] += bq.z; v[3] += bq.w;
                float* dst = out + ((size_t)b * TOK + sPOS[tok]) * EMB + n0 + mt * 16 + quad * 4;
                *(f32x4*)dst = v;
            }
        }
    }
}

// ---- proj_w fp32 -> bf16 transpose: Wt[n][k] = bf16(W[k][n]) ----
__global__ __launch_bounds__(256) void cvt_kernel(
    const float* __restrict__ W, unsigned short* __restrict__ Wt)
{
    int i = blockIdx.x * 256 + threadIdx.x;
    int k = i >> 8, n = i & 255;
    Wt[n * 256 + k] = f2bf(W[i]);
}

// ---- bias+mask table in scores-MFMA C layout: tbl[cls][h][mt*4+nt][lane][r] ----
__global__ __launch_bounds__(256) void tbl_kernel(
    const float* __restrict__ rpb, float* __restrict__ tbl)
{
    int idx = blockIdx.x * 256 + threadIdx.x;      // 131072 total
    int r = idx & 3;
    int lane = (idx >> 2) & 63;
    int cl = lane & 15, quad = lane >> 4;
    int tile = (idx >> 8) & 15;
    int mt = tile >> 2, nt = tile & 3;
    int h = (idx >> 12) & 7;
    int cls = (idx >> 15) & 3;
    int ci = cls >> 1, cj = cls & 1;

    int ktok = mt * 16 + quad * 4 + r;
    int qtok = nt * 16 + cl;

    float v;
    if (ktok >= WD) v = -1e30f;                    // padded key -> exp = 0
    else if (qtok >= WD) v = 0.f;                  // padded query -> finite junk, discarded
    else {
        int qi = qtok / 7, qj = qtok - qi * 7;
        int ki = ktok / 7, kj = ktok - ki * 7;
        v = rpb[((qi - ki + 6) * 13 + (qj - kj + 6)) * NH + h];
        int qreg = (ci ? (qi < 4 ? 1 : 2) : 0) * 3 + (cj ? (qj < 4 ? 1 : 2) : 0);
        int kreg = (ci ? (ki < 4 ? 1 : 2) : 0) * 3 + (cj ? (kj < 4 ? 1 : 2) : 0);
        if (qreg != kreg) v -= 100.f;
    }
    tbl[idx] = v;
}

extern "C" void kernel_launch(void* const* d_in, const int* in_sizes, int n_in,
                              void* d_out, int out_size, void* d_ws, size_t ws_size,
                              hipStream_t stream) {
    const float* x      = (const float*)d_in[0];
    const float* qkv_w  = (const float*)d_in[1];
    const float* qkv_b  = (const float*)d_in[2];
    const float* proj_w = (const float*)d_in[3];
    const float* proj_b = (const float*)d_in[4];
    const float* rpb    = (const float*)d_in[5];
    float* out = (float*)d_out;

    const int B = in_sizes[0] / (TOK * EMB);

    unsigned short* Wt = (unsigned short*)d_ws;                    // 128 KB
    float* tbl = (float*)((char*)d_ws + 131072);                   // 512 KB

    (void)hipFuncSetAttribute(reinterpret_cast<const void*>(&fused_kernel),
                              hipFuncAttributeMaxDynamicSharedMemorySize, LDS_TOTAL);
    cvt_kernel<<<256, 256, 0, stream>>>(proj_w, Wt);
    tbl_kernel<<<512, 256, 0, stream>>>(rpb, tbl);
    fused_kernel<<<B * NWIN, 256, LDS_TOTAL, stream>>>(x, qkv_w, qkv_b, Wt, proj_b, tbl, out);
}